// Round 1
// baseline (2480.000 us; speedup 1.0000x reference)
//
#include <hip/hip_runtime.h>
#include <hip/hip_fp16.h>
#include <cstdint>
#include <cstddef>

// Problem dims
#define Bb 64
#define Tt 12
#define Ff 64
#define Nn 1024
#define Hh 256
#define Gg 768          // 3*H
#define BN 65536        // Bb*Nn rows

using f32x4 = __attribute__((ext_vector_type(4))) float;
using h8    = __attribute__((ext_vector_type(8))) _Float16;

__device__ __forceinline__ float sigm(float x) {
    return 1.0f / (1.0f + __expf(-x));
}
__device__ __forceinline__ float tanh_fast(float x) {
    // tanh(x) = 1 - 2/(1+e^{2x}); saturates correctly for |x| large
    return 1.0f - 2.0f / (1.0f + __expf(2.0f * x));
}

// ---------------------------------------------------------------------------
// Pack W (K x 768 fp32) into per-lane MFMA B-fragment order, fp16.
// Fragment (k32, gi): lane l needs W[k32*32 + 8*(l>>4) + j][gi*16 + (l&15)], j=0..7
// stored contiguously at ((k32*48 + gi)*64 + l)*8 + j.
// ---------------------------------------------------------------------------
__global__ __launch_bounds__(256) void pack_w(
    const float* __restrict__ Wx0, const float* __restrict__ Wh0,
    const float* __restrict__ Wx1, const float* __restrict__ Wh1,
    _Float16* __restrict__ pWx0, _Float16* __restrict__ pWh0,
    _Float16* __restrict__ pWx1, _Float16* __restrict__ pWh1)
{
    int tid = blockIdx.x * 256 + threadIdx.x;
    const int L0 = (Ff / 32) * 48 * 64;   // 6144 lanes for Wx0 (K=64)
    const int L1 = (Hh / 32) * 48 * 64;   // 24576 lanes for K=256 matrices
    const float* src; _Float16* dst; int fl;
    if (tid < L0)                { src = Wx0; dst = pWx0; fl = tid; }
    else if (tid < L0 + L1)      { src = Wh0; dst = pWh0; fl = tid - L0; }
    else if (tid < L0 + 2 * L1)  { src = Wx1; dst = pWx1; fl = tid - L0 - L1; }
    else if (tid < L0 + 3 * L1)  { src = Wh1; dst = pWh1; fl = tid - L0 - 2 * L1; }
    else return;
    int lane = fl & 63;
    int rest = fl >> 6;
    int gi   = rest % 48;
    int k32  = rest / 48;
    int krow = k32 * 32 + 8 * (lane >> 4);
    int gcol = gi * 16 + (lane & 15);
    h8 v;
    #pragma unroll
    for (int j = 0; j < 8; ++j) v[j] = (_Float16)src[(size_t)(krow + j) * Gg + gcol];
    *reinterpret_cast<h8*>(dst + (size_t)fl * 8) = v;
}

// ---------------------------------------------------------------------------
// Transpose x (B,T,F,N) fp32 -> xT (T, B*N, F) fp16 so layer0's K dim (F) is
// contiguous per row.
// ---------------------------------------------------------------------------
__global__ __launch_bounds__(256) void tx_kernel(const float* __restrict__ x,
                                                 _Float16* __restrict__ xT)
{
    int nb = blockIdx.x;    // 0..15 (n block of 64)
    int t  = blockIdx.y;    // 0..11
    int b  = blockIdx.z;    // 0..63
    __shared__ float lds[64][65];
    int tid = threadIdx.x;
    int n0 = nb * 64;
    const float* xp = x + (((size_t)b * Tt + t) * Ff) * Nn + n0;
    #pragma unroll
    for (int it = 0; it < 16; ++it) {
        int idx = it * 256 + tid;
        int f = idx >> 6, n = idx & 63;
        lds[f][n] = xp[(size_t)f * Nn + n];
    }
    __syncthreads();
    int ni = tid >> 2, f0 = (tid & 3) * 16;
    h8 v0, v1;
    #pragma unroll
    for (int j = 0; j < 8; ++j) {
        v0[j] = (_Float16)lds[f0 + j][ni];
        v1[j] = (_Float16)lds[f0 + 8 + j][ni];
    }
    _Float16* dst = xT + ((size_t)t * BN + (size_t)b * Nn + n0 + ni) * Ff + f0;
    reinterpret_cast<h8*>(dst)[0] = v0;
    reinterpret_cast<h8*>(dst)[1] = v1;
}

// ---------------------------------------------------------------------------
// One GRU layer step.  gates = A1@Wx + b  (+ A2@Wh),  h_out = GRU-combine.
// A1: (BN x K1) fp16 row-major (x-part input / lower layer h)
// A2: (BN x 256) fp16 row-major (this layer's previous h; unused if FIRST)
// Tile: WG 512 thr = 8 waves (2 row-groups x 4 ch-groups); 64 rows x 128 ch
// per WG; grid (BN/64, 2).  4 accumulator groups per output elem: r,z,xn,hn.
// No LDS, no barriers; all operands per-lane 16B global loads (weights are
// pre-packed in fragment order, A rows are K-contiguous).
// ---------------------------------------------------------------------------
template<int K1, bool FIRST>
__global__ __launch_bounds__(512, 2) void gru_step(
    const _Float16* __restrict__ A1,
    const _Float16* __restrict__ A2,
    const _Float16* __restrict__ pWx,   // packed (K1/32)*48 frags
    const _Float16* __restrict__ pWh,   // packed (256/32)*48 frags
    const float* __restrict__ bias,     // 768 fp32
    _Float16* __restrict__ hout)        // (BN x 256) fp16
{
    int tid  = threadIdx.x;
    int lane = tid & 63;
    int wid  = tid >> 6;     // 0..7
    int rg   = wid >> 2;     // 0..1 row group (32 rows each)
    int cg   = wid & 3;      // 0..3 channel group (32 ch each)
    int m0   = blockIdx.x * 64 + rg * 32;
    int y    = blockIdx.y;   // channel half (128 ch each)
    int l15  = lane & 15, l4 = lane >> 4;
    int gib  = y * 8 + cg * 2;   // base gi (16-wide col frag) within r-block

    const f32x4 z4 = {0.0f, 0.0f, 0.0f, 0.0f};
    f32x4 aR[2][2], aZ[2][2], aN[2][2], aH[2][2];
    #pragma unroll
    for (int i = 0; i < 2; ++i)
        #pragma unroll
        for (int j = 0; j < 2; ++j) { aR[i][j] = z4; aZ[i][j] = z4; aN[i][j] = z4; aH[i][j] = z4; }

    // ---- phase 1: A1 @ Wx -> r, z, xn ----
    {
        const _Float16* a1p = A1 + (size_t)(m0 + l15) * K1 + 8 * l4;
        #pragma unroll 2
        for (int k0 = 0; k0 < K1; k0 += 32) {
            h8 a0 = *reinterpret_cast<const h8*>(a1p + k0);
            h8 a1 = *reinterpret_cast<const h8*>(a1p + 16 * K1 + k0);
            const _Float16* wp = pWx + ((size_t)(k0 >> 5) * 48) * 512 + (size_t)lane * 8;
            #pragma unroll
            for (int cf = 0; cf < 2; ++cf) {
                h8 bR = *reinterpret_cast<const h8*>(wp + (gib + cf) * 512);
                h8 bZ = *reinterpret_cast<const h8*>(wp + (gib + cf + 16) * 512);
                h8 bN = *reinterpret_cast<const h8*>(wp + (gib + cf + 32) * 512);
                aR[0][cf] = __builtin_amdgcn_mfma_f32_16x16x32_f16(a0, bR, aR[0][cf], 0, 0, 0);
                aR[1][cf] = __builtin_amdgcn_mfma_f32_16x16x32_f16(a1, bR, aR[1][cf], 0, 0, 0);
                aZ[0][cf] = __builtin_amdgcn_mfma_f32_16x16x32_f16(a0, bZ, aZ[0][cf], 0, 0, 0);
                aZ[1][cf] = __builtin_amdgcn_mfma_f32_16x16x32_f16(a1, bZ, aZ[1][cf], 0, 0, 0);
                aN[0][cf] = __builtin_amdgcn_mfma_f32_16x16x32_f16(a0, bN, aN[0][cf], 0, 0, 0);
                aN[1][cf] = __builtin_amdgcn_mfma_f32_16x16x32_f16(a1, bN, aN[1][cf], 0, 0, 0);
            }
        }
    }
    // ---- phase 2: A2 @ Wh -> r, z, hn ----
    if (!FIRST) {
        const _Float16* a2p = A2 + (size_t)(m0 + l15) * Hh + 8 * l4;
        #pragma unroll 2
        for (int k0 = 0; k0 < Hh; k0 += 32) {
            h8 a0 = *reinterpret_cast<const h8*>(a2p + k0);
            h8 a1 = *reinterpret_cast<const h8*>(a2p + 16 * Hh + k0);
            const _Float16* wp = pWh + ((size_t)(k0 >> 5) * 48) * 512 + (size_t)lane * 8;
            #pragma unroll
            for (int cf = 0; cf < 2; ++cf) {
                h8 bR = *reinterpret_cast<const h8*>(wp + (gib + cf) * 512);
                h8 bZ = *reinterpret_cast<const h8*>(wp + (gib + cf + 16) * 512);
                h8 bN = *reinterpret_cast<const h8*>(wp + (gib + cf + 32) * 512);
                aR[0][cf] = __builtin_amdgcn_mfma_f32_16x16x32_f16(a0, bR, aR[0][cf], 0, 0, 0);
                aR[1][cf] = __builtin_amdgcn_mfma_f32_16x16x32_f16(a1, bR, aR[1][cf], 0, 0, 0);
                aZ[0][cf] = __builtin_amdgcn_mfma_f32_16x16x32_f16(a0, bZ, aZ[0][cf], 0, 0, 0);
                aZ[1][cf] = __builtin_amdgcn_mfma_f32_16x16x32_f16(a1, bZ, aZ[1][cf], 0, 0, 0);
                aH[0][cf] = __builtin_amdgcn_mfma_f32_16x16x32_f16(a0, bN, aH[0][cf], 0, 0, 0);
                aH[1][cf] = __builtin_amdgcn_mfma_f32_16x16x32_f16(a1, bN, aH[1][cf], 0, 0, 0);
            }
        }
    }

    // ---- epilogue: GRU combine ----
    // D frag: col = l&15 (channel), row = 4*(l>>4) + q   [measured m89/m91]
    int cb = y * 128 + cg * 32;
    #pragma unroll
    for (int cf = 0; cf < 2; ++cf) {
        int c = cb + cf * 16 + l15;
        float brv = bias[c], bzv = bias[Hh + c], bnv = bias[2 * Hh + c];
        #pragma unroll
        for (int mf = 0; mf < 2; ++mf) {
            int rbase = m0 + mf * 16 + 4 * l4;
            #pragma unroll
            for (int q = 0; q < 4; ++q) {
                size_t idx = (size_t)(rbase + q) * Hh + c;
                float r  = sigm(aR[mf][cf][q] + brv);
                float zt = sigm(aZ[mf][cf][q] + bzv);
                float hn = FIRST ? 0.0f : aH[mf][cf][q];
                float n  = tanh_fast(aN[mf][cf][q] + bnv + r * hn);
                float hp = FIRST ? 0.0f : (float)A2[idx];
                float hv = n + zt * (hp - n);
                hout[idx] = (_Float16)hv;
            }
        }
    }
}

// ---------------------------------------------------------------------------
// Final: h (B*N x H) fp16 -> out (2,B,H,N) fp32, coalesced both sides via LDS.
// ---------------------------------------------------------------------------
__global__ __launch_bounds__(256) void tout_kernel(const _Float16* __restrict__ hA,
                                                   const _Float16* __restrict__ hB,
                                                   float* __restrict__ out)
{
    int nb = blockIdx.x;          // 0..15
    int cb = blockIdx.y;          // 0..3
    int lb = blockIdx.z;          // 0..127  (layer*64 + b)
    int l = lb >> 6, b = lb & 63;
    const _Float16* h = l ? hB : hA;
    __shared__ float lds[64][65];
    int tid = threadIdx.x;
    int n0 = nb * 64, c0 = cb * 64;
    #pragma unroll
    for (int it = 0; it < 16; ++it) {
        int idx = it * 256 + tid;
        int ni = idx >> 6, c = idx & 63;
        lds[ni][c] = (float)h[(size_t)(b * Nn + n0 + ni) * Hh + c0 + c];
    }
    __syncthreads();
    #pragma unroll
    for (int it = 0; it < 16; ++it) {
        int idx = it * 256 + tid;
        int ci = idx >> 6, nj = idx & 63;
        out[(((size_t)l * Bb + b) * Hh + c0 + ci) * Nn + n0 + nj] = lds[nj][ci];
    }
}

// ---------------------------------------------------------------------------
extern "C" void kernel_launch(void* const* d_in, const int* in_sizes, int n_in,
                              void* d_out, int out_size, void* d_ws, size_t ws_size,
                              hipStream_t stream)
{
    const float* x   = (const float*)d_in[0];
    const float* Wx0 = (const float*)d_in[1];
    const float* Wh0 = (const float*)d_in[2];
    const float* b0  = (const float*)d_in[3];
    const float* Wx1 = (const float*)d_in[4];
    const float* Wh1 = (const float*)d_in[5];
    const float* b1  = (const float*)d_in[6];
    float* out = (float*)d_out;

    char* ws = (char*)d_ws;
    size_t off = 0;
    auto alloc = [&](size_t bytes) -> void* {
        void* p = ws + off;
        off += (bytes + 255) & ~(size_t)255;
        return p;
    };
    _Float16* xT   = (_Float16*)alloc((size_t)Tt * BN * Ff * 2);   // 100.7 MB
    _Float16* hA0  = (_Float16*)alloc((size_t)BN * Hh * 2);        // 32 MB each
    _Float16* hA1  = (_Float16*)alloc((size_t)BN * Hh * 2);
    _Float16* hB0  = (_Float16*)alloc((size_t)BN * Hh * 2);
    _Float16* hB1  = (_Float16*)alloc((size_t)BN * Hh * 2);
    _Float16* pWx0 = (_Float16*)alloc((size_t)(Ff / 32) * 48 * 512 * 2);
    _Float16* pWh0 = (_Float16*)alloc((size_t)(Hh / 32) * 48 * 512 * 2);
    _Float16* pWx1 = (_Float16*)alloc((size_t)(Hh / 32) * 48 * 512 * 2);
    _Float16* pWh1 = (_Float16*)alloc((size_t)(Hh / 32) * 48 * 512 * 2);

    pack_w<<<312, 256, 0, stream>>>(Wx0, Wh0, Wx1, Wh1, pWx0, pWh0, pWx1, pWh1);
    tx_kernel<<<dim3(16, Tt, Bb), 256, 0, stream>>>(x, xT);

    _Float16* hA[2] = {hA0, hA1};
    _Float16* hB[2] = {hB0, hB1};
    for (int t = 0; t < Tt; ++t) {
        const _Float16* xt = xT + (size_t)t * BN * Ff;
        _Float16* hAw = hA[t & 1];
        const _Float16* hAr = hA[(t + 1) & 1];
        _Float16* hBw = hB[t & 1];
        const _Float16* hBr = hB[(t + 1) & 1];
        dim3 g(BN / 64, 2);
        if (t == 0) {
            gru_step<Ff, true ><<<g, 512, 0, stream>>>(xt,  hAr, pWx0, pWh0, b0, hAw);
            gru_step<Hh, true ><<<g, 512, 0, stream>>>(hAw, hBr, pWx1, pWh1, b1, hBw);
        } else {
            gru_step<Ff, false><<<g, 512, 0, stream>>>(xt,  hAr, pWx0, pWh0, b0, hAw);
            gru_step<Hh, false><<<g, 512, 0, stream>>>(hAw, hBr, pWx1, pWh1, b1, hBw);
        }
    }
    tout_kernel<<<dim3(16, 4, 2 * Bb), 256, 0, stream>>>(hA[(Tt - 1) & 1], hB[(Tt - 1) & 1], out);
}